// Round 1
// baseline (179.071 us; speedup 1.0000x reference)
//
#include <hip/hip_runtime.h>

#define BN_EPS 1e-3f

typedef __attribute__((ext_vector_type(8))) short bf16x8;
typedef __attribute__((ext_vector_type(4))) float f32x4;

__device__ inline unsigned short f2b(float f) {
    unsigned int u = __float_as_uint(f);
    unsigned int r = (u + 0x7fffu + ((u >> 16) & 1u)) >> 16;
    return (unsigned short)r;
}
__device__ inline float b2f(unsigned short h) {
    return __uint_as_float(((unsigned int)h) << 16);
}

// ---------------------------------------------------------------------------
// k_prep: Bt[n][k] = bf16 of (n<256 ? Wi[k][n] : Wr[k][n-256])   [320,256]
//         Wst[n][k] = bf16 of Ws[k][n]                            [144,64]
// ---------------------------------------------------------------------------
__global__ void k_prep(const float* __restrict__ Wi, const float* __restrict__ Wr,
                       const float* __restrict__ Ws,
                       unsigned short* __restrict__ Bt, unsigned short* __restrict__ Wst) {
    int t = blockIdx.x * 256 + threadIdx.x;
    if (t < 320 * 256) {
        int n = t >> 8, k = t & 255;
        float v = (n < 256) ? Wi[k * 256 + n] : Wr[k * 64 + (n - 256)];
        Bt[t] = f2b(v);
    } else {
        int t2 = t - 320 * 256;
        if (t2 < 144 * 64) {
            int n = t2 >> 6, k = t2 & 63;
            Wst[t2] = f2b(Ws[k * 144 + n]);
        }
    }
}

// ---------------------------------------------------------------------------
// k_fused: one block = one 16x8 output tile (halo 18x10 = 180 px).
// 1024 threads (16 waves) instead of 512: same LDS footprint, double the
// waves/SIMD (2->4) to hide barrier/LDS/global latency.
//   phase 1 (6 chunks of 32 halo rows, in-place LDS): each wave owns ONE
//       B column-tile (n = wv*16..) and both m-tiles; waves 0-3 additionally
//       own the r column-tiles.
//   phase 2: w = r @ Ws^T (+bs); wave -> (m = wv&7, j-half = wv>>3).
//   phase 3: verified contiguous-run gather, 2 (px,g) units per thread.
// LDS (u16): XI 180x264 | RS 180x72 | WL 128x144  = 157,824 B -> 1 block/CU.
// ---------------------------------------------------------------------------
#define XIP 264
#define RS_OFF (180 * XIP)            // 47520
#define RSP 72
#define WL_OFF (RS_OFF + 180 * RSP)   // 60480
#define SMN (WL_OFF + 128 * 144)      // 78912 u16 = 157,824 B

__global__ __launch_bounds__(1024, 4) void k_fused(
    const float* __restrict__ x, const unsigned short* __restrict__ Bt,
    const unsigned short* __restrict__ Wst,
    const float* __restrict__ bi, const float* __restrict__ br,
    const float* __restrict__ gamma, const float* __restrict__ beta,
    const float* __restrict__ mean, const float* __restrict__ var,
    const float* __restrict__ bs, float* __restrict__ out)
{
    __shared__ __attribute__((aligned(16))) unsigned short sm[SMN];
    const int tid = threadIdx.x;
    const int bx = blockIdx.x;
    const int w0 = (bx & 7) * 16;
    const int h0 = ((bx >> 3) & 15) * 8;
    const int bb = bx >> 7;

    const int wv = tid >> 6;          // 0..15
    const int lane = tid & 63;
    const int col = lane & 15;
    const int quad = lane >> 4;

    // ---- per-wave constants & register-resident B fragments ----
    const float bi_v = bi[wv * 16 + col];
    const int dcl = (wv & 3) * 16 + col;       // r-column (valid when wv<4)
    const float brd = br[dcl];
    const float md  = mean[dcl];
    const float sc  = gamma[dcl] * rsqrtf(var[dcl] + BN_EPS);
    const float btv = beta[dcl];

    bf16x8 bxA[8], brr[8];
    {
        const unsigned short* p0 = &Bt[(wv * 16 + col) * 256];
#pragma unroll
        for (int kc = 0; kc < 8; ++kc)
            bxA[kc] = *(const bf16x8*)&p0[kc * 32 + quad * 8];
        if (wv < 4) {
            const unsigned short* pr = &Bt[((16 + wv) * 16 + col) * 256];
#pragma unroll
            for (int kc = 0; kc < 8; ++kc)
                brr[kc] = *(const bf16x8*)&pr[kc * 32 + quad * 8];
        }
    }

    // ---- staging: 32 threads/row, each 8 channels {chq..+3, chq+128..+131} ----
    const int chq = (tid & 31) * 4;

    // prologue: stage chunk 0 (rows 0..31)
    {
        int hp = tid >> 5;                       // 0..31
        int r = hp / 18, cc = hp - r * 18;
        int gh = h0 - 1 + r, gw = w0 - 1 + cc;
        bool ok = ((unsigned)gh < 128u) && ((unsigned)gw < 128u);
        float4 v0, v1;
        if (ok) {
            const float* src = x + (((long long)(bb * 128 + gh)) * 128 + gw) * 256 + chq;
            v0 = *(const float4*)&src[0];
            v1 = *(const float4*)&src[128];
        } else {
            v0 = (float4){0.f, 0.f, 0.f, 0.f};
            v1 = v0;
        }
        uint2 pk;
        pk.x = (unsigned)f2b(v0.x) | ((unsigned)f2b(v0.y) << 16);
        pk.y = (unsigned)f2b(v0.z) | ((unsigned)f2b(v0.w) << 16);
        *(uint2*)&sm[hp * XIP + chq] = pk;
        pk.x = (unsigned)f2b(v1.x) | ((unsigned)f2b(v1.y) << 16);
        pk.y = (unsigned)f2b(v1.z) | ((unsigned)f2b(v1.w) << 16);
        *(uint2*)&sm[hp * XIP + chq + 128] = pk;
    }
    __syncthreads();

    // ---- chunk loop ----
    for (int c = 0; c < 6; ++c) {
        // issue global loads for chunk c+1 (overlap with MFMAs below)
        float4 vn0, vn1;
        int hp_n = 192;
        if (c < 5) {
            hp_n = (c + 1) * 32 + (tid >> 5);
            int r = hp_n / 18, cc = hp_n - r * 18;
            int gh = h0 - 1 + r, gw = w0 - 1 + cc;
            bool ok = (hp_n < 180) && ((unsigned)gh < 128u) && ((unsigned)gw < 128u);
            if (ok) {
                const float* src = x + (((long long)(bb * 128 + gh)) * 128 + gw) * 256 + chq;
                vn0 = *(const float4*)&src[0];
                vn1 = *(const float4*)&src[128];
            } else {
                vn0 = (float4){0.f, 0.f, 0.f, 0.f};
                vn1 = vn0;
            }
        }

        // MFMA chunk c: wave's single n-tile over both m-tiles
        f32x4 acc0 = {0.f, 0.f, 0.f, 0.f}, acc1 = acc0;
        f32x4 ar0 = acc0, ar1 = acc0;
        {
            const int rowA0 = (c * 32 + col) * XIP;
            const int rowA1 = rowA0 + 16 * XIP;
#pragma unroll
            for (int kc = 0; kc < 8; ++kc) {
                const int kb = kc * 32 + quad * 8;
                bf16x8 a0 = *(const bf16x8*)&sm[rowA0 + kb];
                bf16x8 a1 = *(const bf16x8*)&sm[rowA1 + kb];
                acc0 = __builtin_amdgcn_mfma_f32_16x16x32_bf16(a0, bxA[kc], acc0, 0, 0, 0);
                acc1 = __builtin_amdgcn_mfma_f32_16x16x32_bf16(a1, bxA[kc], acc1, 0, 0, 0);
                if (wv < 4) {
                    ar0 = __builtin_amdgcn_mfma_f32_16x16x32_bf16(a0, brr[kc], ar0, 0, 0, 0);
                    ar1 = __builtin_amdgcn_mfma_f32_16x16x32_bf16(a1, brr[kc], ar1, 0, 0, 0);
                }
            }
        }
        __syncthreads();   // all reads of rows_c done

        // write staged A for chunk c+1 (disjoint rows)
        if (c < 5 && hp_n < 180) {
            uint2 pk;
            pk.x = (unsigned)f2b(vn0.x) | ((unsigned)f2b(vn0.y) << 16);
            pk.y = (unsigned)f2b(vn0.z) | ((unsigned)f2b(vn0.w) << 16);
            *(uint2*)&sm[hp_n * XIP + chq] = pk;
            pk.x = (unsigned)f2b(vn1.x) | ((unsigned)f2b(vn1.y) << 16);
            pk.y = (unsigned)f2b(vn1.z) | ((unsigned)f2b(vn1.w) << 16);
            *(uint2*)&sm[hp_n * XIP + chq + 128] = pk;
        }

        // epilogue chunk c: xi -> XI rows_c, r -> RS rows_c
        {
            const int n0 = wv * 16 + col;
            const int rb = c * 32 + quad * 4;
#pragma unroll
            for (int rg = 0; rg < 4; ++rg) {
                const int r0 = rb + rg, r1 = r0 + 16;
                if (r0 < 180) sm[r0 * XIP + n0] = f2b(acc0[rg] + bi_v);
                if (r1 < 180) sm[r1 * XIP + n0] = f2b(acc1[rg] + bi_v);
            }
            if (wv < 4) {
#pragma unroll
                for (int rg = 0; rg < 4; ++rg) {
                    const int r0 = rb + rg, r1 = r0 + 16;
                    if (r0 < 180) {
                        float v = (ar0[rg] + brd - md) * sc + btv;
                        sm[RS_OFF + r0 * RSP + dcl] = f2b(fmaxf(v, 0.f));
                    }
                    if (r1 < 180) {
                        float v = (ar1[rg] + brd - md) * sc + btv;
                        sm[RS_OFF + r1 * RSP + dcl] = f2b(fmaxf(v, 0.f));
                    }
                }
            }
        }
        __syncthreads();
    }

    // ---- phase 2: w = r @ Wst^T (+bs); wave -> (m = wv&7, j-half = wv>>3) ----
    // waves 0-7 do j = 0..4, waves 8-15 do j = 4..8 (j=4 duplicated, identical
    // inputs -> identical value, benign same-value write).
    {
        const int m = wv & 7;
        const int jbase = (wv >> 3) * 4;
        f32x4 wacc[5];
#pragma unroll
        for (int jj = 0; jj < 5; ++jj) wacc[jj] = (f32x4){0.f, 0.f, 0.f, 0.f};
        // interior px p = m*16 + col -> halo row 19 + m*18 + col
        const int arow = (19 + m * 18 + col) * RSP;
#pragma unroll
        for (int kc = 0; kc < 2; ++kc) {
            const int kb = kc * 32 + quad * 8;
            bf16x8 ra = *(const bf16x8*)&sm[RS_OFF + arow + kb];
#pragma unroll
            for (int jj = 0; jj < 5; ++jj) {
                bf16x8 wb = *(const bf16x8*)&Wst[((jbase + jj) * 16 + col) * 64 + kb];
                wacc[jj] = __builtin_amdgcn_mfma_f32_16x16x32_bf16(ra, wb, wacc[jj], 0, 0, 0);
            }
        }
#pragma unroll
        for (int jj = 0; jj < 5; ++jj) {
            const int n = (jbase + jj) * 16 + col;
            const float bv = bs[n];
            const int prow = m * 16 + quad * 4;
#pragma unroll
            for (int rg = 0; rg < 4; ++rg)
                sm[WL_OFF + (prow + rg) * 144 + n] = f2b(wacc[jj][rg] + bv);
        }
    }
    __syncthreads();

    // ---- phase 3: gather (2 units per thread) ----
    {
        const int g = tid & 15;
        const int pb = tid >> 4;               // 0..63

        const int idx0 = g * 144;
        const int kp0  = idx0 >> 8;
        const int c0   = idx0 & 255;           // multiple of 16
        int len1 = 256 - c0; if (len1 > 144) len1 = 144;
        const int kp1  = kp0 + 1;
        const int koff0 = (kp0 / 3) * 18 + (kp0 % 3);
        const int koff1 = (kp1 <= 8) ? ((kp1 / 3) * 18 + (kp1 % 3)) : 0;

#pragma unroll
        for (int jj = 0; jj < 2; ++jj) {
            const int p = pb + 64 * jj;        // interior px 0..127
            const int phb = (p >> 4) * 18 + (p & 15);
            const int base0 = (phb + koff0) * XIP + c0;
            const int base1 = (phb + koff1) * XIP;

            float wf[9];
#pragma unroll
            for (int kk = 0; kk < 9; ++kk)
                wf[kk] = b2f(sm[WL_OFF + p * 144 + g * 9 + kk]);

            float res[16];
            {
                int4 xv[9];
#pragma unroll
                for (int i = 0; i < 9; ++i) {
                    const int e = i * 8;
                    const int addr = (e < len1) ? (base0 + e) : (base1 + (e - len1));
                    xv[i] = *(const int4*)&sm[addr];
                }
#pragma unroll
                for (int f2 = 0; f2 < 8; ++f2) {
                    float a = 0.f;
#pragma unroll
                    for (int kk = 0; kk < 9; ++kk) {
                        const int e = f2 * 9 + kk;
                        const int word = ((const int*)&xv[e >> 3])[(e >> 1) & 3];
                        const unsigned short u = (e & 1) ? (unsigned short)(((unsigned)word) >> 16)
                                                         : (unsigned short)(word & 0xffff);
                        a += wf[kk] * b2f(u);
                    }
                    res[f2] = a;
                }
            }
            {
                int4 xv[9];
#pragma unroll
                for (int i = 9; i < 18; ++i) {
                    const int e = i * 8;
                    const int addr = (e < len1) ? (base0 + e) : (base1 + (e - len1));
                    xv[i - 9] = *(const int4*)&sm[addr];
                }
#pragma unroll
                for (int f2 = 8; f2 < 16; ++f2) {
                    float a = 0.f;
#pragma unroll
                    for (int kk = 0; kk < 9; ++kk) {
                        const int e = f2 * 9 + kk;
                        const int i = (e >> 3) - 9;
                        const int word = ((const int*)&xv[i])[(e >> 1) & 3];
                        const unsigned short u = (e & 1) ? (unsigned short)(((unsigned)word) >> 16)
                                                         : (unsigned short)(word & 0xffff);
                        a += wf[kk] * b2f(u);
                    }
                    res[f2] = a;
                }
            }

            const long long orow =
                (((long long)(bb * 128 + h0 + (p >> 4))) * 128 + (w0 + (p & 15))) * 256 + g * 16;
#pragma unroll
            for (int q = 0; q < 4; ++q) {
                float4 o = {res[q * 4 + 0], res[q * 4 + 1], res[q * 4 + 2], res[q * 4 + 3]};
                *(float4*)&out[orow + q * 4] = o;
            }
        }
    }
}

// ---------------------------------------------------------------------------
extern "C" void kernel_launch(void* const* d_in, const int* in_sizes, int n_in,
                              void* d_out, int out_size, void* d_ws, size_t ws_size,
                              hipStream_t stream) {
    const float* x     = (const float*)d_in[0];
    const float* Wr    = (const float*)d_in[1];
    const float* br    = (const float*)d_in[2];
    const float* gamma = (const float*)d_in[3];
    const float* beta  = (const float*)d_in[4];
    const float* mean  = (const float*)d_in[5];
    const float* var   = (const float*)d_in[6];
    const float* Ws    = (const float*)d_in[7];
    const float* bs    = (const float*)d_in[8];
    const float* Wi    = (const float*)d_in[9];
    const float* bi    = (const float*)d_in[10];
    float* out = (float*)d_out;

    unsigned char* ws = (unsigned char*)d_ws;
    unsigned short* Bt  = (unsigned short*)(ws + 0);        // 320*256*2 = 163,840 B
    unsigned short* Wst = (unsigned short*)(ws + 163840);   // 144*64*2  =  18,432 B

    k_prep<<<dim3(356), dim3(256), 0, stream>>>(Wi, Wr, Ws, Bt, Wst);
    k_fused<<<dim3(512), dim3(1024), 0, stream>>>(
        x, Bt, Wst, bi, br, gamma, beta, mean, var, bs, out);
}